// Round 1
// baseline (475.631 us; speedup 1.0000x reference)
//
#include <hip/hip_runtime.h>

// ---------------- problem constants ----------------
#define G_DIM 3072
#define P_DIM 1024
#define ALPHA 0.1f

typedef __attribute__((ext_vector_type(8))) __bf16 bf16x8;
typedef __attribute__((ext_vector_type(4))) float  f32x4;

// workspace layout (bytes)
#define GG2      ((size_t)G_DIM * G_DIM * 2)          // bf16 G×G = 18,874,368 B
#define SB_OFF   ((size_t)0)
#define ST_OFF   (GG2)
#define S2_OFF   (2 * GG2)
#define W_OFF    (3 * GG2)
#define X_OFF    ((size_t)0)                           // overlaps SB/ST/S2 after they die

// ---------------- softmax: S = alpha * softmax(scores, -inf diag) ----------------
__global__ __launch_bounds__(256) void row_softmax_k(const float* __restrict__ gg,
                                                     __bf16* __restrict__ S) {
  const int i = blockIdx.x;
  const float* row = gg + (size_t)i * G_DIM * 2;  // [G][2], channel 1
  const int tid = threadIdx.x;
  const int lane = tid & 63, wave = tid >> 6;

  float v[12];
  float m = -INFINITY;
#pragma unroll
  for (int t = 0; t < 12; ++t) {
    int j = tid + t * 256;
    float x = row[2 * j + 1];
    if (j == i) x = -INFINITY;
    v[t] = x;
    m = fmaxf(m, x);
  }
#pragma unroll
  for (int o = 32; o; o >>= 1) m = fmaxf(m, __shfl_xor(m, o));
  __shared__ float red[4];
  if (lane == 0) red[wave] = m;
  __syncthreads();
  m = fmaxf(fmaxf(red[0], red[1]), fmaxf(red[2], red[3]));

  float s = 0.f;
#pragma unroll
  for (int t = 0; t < 12; ++t) {
    v[t] = __expf(v[t] - m);   // exp(-inf - m) = 0 handles diag
    s += v[t];
  }
#pragma unroll
  for (int o = 32; o; o >>= 1) s += __shfl_xor(s, o);
  __syncthreads();
  if (lane == 0) red[wave] = s;
  __syncthreads();
  s = red[0] + red[1] + red[2] + red[3];

  const float scale = ALPHA / s;
  __bf16* out = S + (size_t)i * G_DIM;
#pragma unroll
  for (int t = 0; t < 12; ++t) {
    int j = tid + t * 256;
    out[j] = (__bf16)(v[t] * scale);
  }
}

// ---------------- bf16 transpose ----------------
__global__ void transpose_k(const __bf16* __restrict__ in, __bf16* __restrict__ out) {
  __shared__ __bf16 t[32][33];
  const int bx = blockIdx.x * 32, by = blockIdx.y * 32;
  const int tx = threadIdx.x, ty = threadIdx.y;
#pragma unroll
  for (int k = 0; k < 32; k += 8)
    t[ty + k][tx] = in[(size_t)(by + ty + k) * G_DIM + bx + tx];
  __syncthreads();
#pragma unroll
  for (int k = 0; k < 32; k += 8)
    out[(size_t)(bx + ty + k) * G_DIM + by + tx] = t[tx][ty + k];
}

// ---------------- deinterleave channels into X [2*4096][G] bf16 ----------------
__global__ __launch_bounds__(256) void deinterleave_k(const float* __restrict__ pg,
                                                      const float* __restrict__ gg,
                                                      __bf16* __restrict__ X) {
  const int rr = blockIdx.x;  // 0..4095
  const float* src = (rr < P_DIM) ? (pg + (size_t)rr * G_DIM * 2)
                                  : (gg + (size_t)(rr - P_DIM) * G_DIM * 2);
  __bf16* x0 = X + (size_t)rr * G_DIM;
  __bf16* x1 = X + (size_t)(4096 + rr) * G_DIM;
  for (int t = threadIdx.x; t < G_DIM; t += 256) {
    float2 p = ((const float2*)src)[t];
    x0[t] = (__bf16)p.x;
    x1[t] = (__bf16)p.y;
  }
}

// ---------------- staged global->LDS copy, pre-swizzled source (rule #21) ----------
// LDS tile: [128 rows][64 k] bf16 = 16 KiB, linear dest; read applies slot ^= (row&7)
__device__ __forceinline__ void stage128x64(const __bf16* __restrict__ src, size_t row0,
                                            int K, int k0, char* lds, int wave, int lane) {
#pragma unroll
  for (int q = 0; q < 4; ++q) {
    int seg = wave * 4 + q;
    int Lb = seg << 10;            // wave-uniform LDS byte base
    int L = Lb + lane * 16;        // this lane's dest byte
    int r = L >> 7;                // tile row
    int slot = ((L >> 4) & 7) ^ (r & 7);   // inverse swizzle on SOURCE
    const __bf16* g = src + (row0 + (size_t)r) * (size_t)K + (size_t)(k0 + slot * 8);
    __builtin_amdgcn_global_load_lds((const __attribute__((address_space(1))) void*)g,
                                     (__attribute__((address_space(3))) void*)(lds + Lb),
                                     16, 0, 0);
  }
}

// ---------------- NT GEMM: C[i,j] = sum_k A[i,k]*B[j,k] ----------------
// MODE 0: C bf16 = acc                                  (S2 = S * St^T)
// MODE 1: C bf16 = 0.9*(acc + e0[i,j] + e1[i,j])        (W_adj)
// MODE 2: d_out f32 interleaved = acc + 0.9*orig f32    (propagate)
template <int MODE>
__global__ __launch_bounds__(256) void gemm_nt(const __bf16* __restrict__ A,
                                               const __bf16* __restrict__ B,
                                               void* __restrict__ C,
                                               const __bf16* __restrict__ e0,
                                               const __bf16* __restrict__ e1,
                                               const float* __restrict__ pgin,
                                               const float* __restrict__ ggin,
                                               int M, int N, int K) {
  __shared__ int4 smem[2048];  // 32 KiB
  char* As = (char*)smem;
  char* Bs = (char*)smem + 16384;

  const int tid = threadIdx.x;
  const int wave = tid >> 6, lane = tid & 63;
  const int wm = wave >> 1, wn = wave & 1;   // 2x2 waves, each 64x64
  const int lr = lane & 15, g4 = lane >> 4;

  const size_t arow0 = (size_t)blockIdx.y * 128;
  const size_t brow0 = (size_t)blockIdx.x * 128;

  f32x4 acc[4][4] = {};

  const int nkt = K / 64;
  for (int kt = 0; kt < nkt; ++kt) {
    const int k0 = kt * 64;
    stage128x64(A, arow0, K, k0, As, wave, lane);
    stage128x64(B, brow0, K, k0, Bs, wave, lane);
    __syncthreads();   // drains vmcnt(0) before barrier (compiler-inserted)

#pragma unroll
    for (int ks = 0; ks < 2; ++ks) {
      const int sA = (((ks * 4 + g4) ^ (lr & 7)) * 16);
      bf16x8 av[4], bv[4];
#pragma unroll
      for (int mf = 0; mf < 4; ++mf)
        av[mf] = *(const bf16x8*)(As + (wm * 64 + mf * 16 + lr) * 128 + sA);
#pragma unroll
      for (int nf = 0; nf < 4; ++nf)
        bv[nf] = *(const bf16x8*)(Bs + (wn * 64 + nf * 16 + lr) * 128 + sA);
#pragma unroll
      for (int mf = 0; mf < 4; ++mf)
#pragma unroll
        for (int nf = 0; nf < 4; ++nf)
          acc[mf][nf] = __builtin_amdgcn_mfma_f32_16x16x32_bf16(av[mf], bv[nf],
                                                                acc[mf][nf], 0, 0, 0);
    }
    __syncthreads();
  }

  // epilogue — C/D layout: col = lane&15, row = (lane>>4)*4 + reg  [measured m89/m91]
  const int r0 = (int)arow0 + wm * 64;
  const int c0 = (int)brow0 + wn * 64;
#pragma unroll
  for (int mf = 0; mf < 4; ++mf) {
#pragma unroll
    for (int nf = 0; nf < 4; ++nf) {
      const int col = c0 + nf * 16 + lr;
#pragma unroll
      for (int jj = 0; jj < 4; ++jj) {
        const int row = r0 + mf * 16 + g4 * 4 + jj;
        float v = acc[mf][nf][jj];
        if constexpr (MODE == 0) {
          ((__bf16*)C)[(size_t)row * N + col] = (__bf16)v;
        } else if constexpr (MODE == 1) {
          float w = 0.9f * (v + (float)e0[(size_t)row * N + col]
                              + (float)e1[(size_t)row * N + col]);
          ((__bf16*)C)[(size_t)row * N + col] = (__bf16)w;
        } else {
          const int c = row >> 12;        // channel (M = 2*4096)
          const int rr = row & 4095;
          float* dst = (float*)C;
          const float* src;
          size_t idx;
          if (rr < P_DIM) {
            idx = ((size_t)rr * G_DIM + col) * 2 + c;
            src = pgin;
          } else {
            idx = ((size_t)(rr - P_DIM) * G_DIM + col) * 2 + c;
            src = ggin;
            dst += (size_t)P_DIM * G_DIM * 2;
          }
          dst[idx] = v + 0.9f * src[idx];
        }
      }
    }
  }
}

// ---------------- launch ----------------
extern "C" void kernel_launch(void* const* d_in, const int* in_sizes, int n_in,
                              void* d_out, int out_size, void* d_ws, size_t ws_size,
                              hipStream_t stream) {
  const float* pg = (const float*)d_in[0];  // [P,G,2] f32
  const float* gg = (const float*)d_in[1];  // [G,G,2] f32
  float* out = (float*)d_out;

  char* ws = (char*)d_ws;
  __bf16* S  = (__bf16*)(ws + SB_OFF);
  __bf16* St = (__bf16*)(ws + ST_OFF);   // also reused for S2^T
  __bf16* S2 = (__bf16*)(ws + S2_OFF);
  __bf16* W  = (__bf16*)(ws + W_OFF);
  __bf16* X  = (__bf16*)(ws + X_OFF);    // overlaps S/St/S2 (dead by then)

  // 1. S = alpha * softmax(gg[:,:,1], -inf diag)      [G,G] bf16
  row_softmax_k<<<G_DIM, 256, 0, stream>>>(gg, S);
  // 2. St = S^T
  transpose_k<<<dim3(96, 96), dim3(32, 8), 0, stream>>>(S, St);
  // 3. S2 = S * S   (NT: A=S, B=St)
  gemm_nt<0><<<dim3(24, 24), 256, 0, stream>>>(S, St, S2, nullptr, nullptr,
                                               nullptr, nullptr, G_DIM, G_DIM, G_DIM);
  // 4. S2t = S2^T (into St buffer)
  transpose_k<<<dim3(96, 96), dim3(32, 8), 0, stream>>>(S2, St);
  // 5. W_adj = 0.9*(S*S2 + S + S2)   (NT: A=S, B=S2t; epilogue adds S,S2)
  gemm_nt<1><<<dim3(24, 24), 256, 0, stream>>>(S, St, W, S, S2,
                                               nullptr, nullptr, G_DIM, G_DIM, G_DIM);
  // 6. X[c*4096+rr][g] = bf16(src[rr][g][c])
  deinterleave_k<<<4096, 256, 0, stream>>>(pg, gg, X);
  // 7. out = X * W_adj^T + 0.9 * X_f32, interleaved into d_out
  gemm_nt<2><<<dim3(24, 64), 256, 0, stream>>>(X, W, out, nullptr, nullptr,
                                               pg, gg, 8192, G_DIM, G_DIM);
  (void)in_sizes; (void)n_in; (void)out_size; (void)ws_size;
}

// Round 2
// 357.100 us; speedup vs baseline: 1.3319x; 1.3319x over previous
//
#include <hip/hip_runtime.h>

// ---------------- problem constants ----------------
#define G_DIM 3072
#define P_DIM 1024
#define ALPHA 0.1f

typedef __attribute__((ext_vector_type(8))) __bf16 bf16x8;
typedef __attribute__((ext_vector_type(4))) float  f32x4;

// workspace layout (bytes), peak 69.2 MB (< 75.5 MB proven available)
//   phase 1 (softmax/transpose/W-gemm): S=[0,18.9M) St=[18.9M,37.7M) W=[50.3M,69.2M)
//   phase 2 (deinterleave/propagate):   X=[0,50.3M) overlays dead S,St ; W live
#define GG2      ((size_t)G_DIM * G_DIM * 2)          // bf16 G×G = 18,874,368 B
#define S_OFF    ((size_t)0)
#define ST_OFF   (GG2)
#define X_OFF    ((size_t)0)
#define XBYTES   ((size_t)8192 * G_DIM * 2)           // 50,331,648 B
#define W_OFF    (XBYTES)

// ---------------- softmax: S = alpha * softmax(scores, -inf diag) ----------------
__global__ __launch_bounds__(256) void row_softmax_k(const float* __restrict__ gg,
                                                     __bf16* __restrict__ S) {
  const int i = blockIdx.x;
  const float* row = gg + (size_t)i * G_DIM * 2;  // [G][2], channel 1
  const int tid = threadIdx.x;
  const int lane = tid & 63, wave = tid >> 6;

  float v[12];
  float m = -INFINITY;
#pragma unroll
  for (int t = 0; t < 12; ++t) {
    int j = tid + t * 256;
    float x = row[2 * j + 1];
    if (j == i) x = -INFINITY;
    v[t] = x;
    m = fmaxf(m, x);
  }
#pragma unroll
  for (int o = 32; o; o >>= 1) m = fmaxf(m, __shfl_xor(m, o));
  __shared__ float red[4];
  if (lane == 0) red[wave] = m;
  __syncthreads();
  m = fmaxf(fmaxf(red[0], red[1]), fmaxf(red[2], red[3]));

  float s = 0.f;
#pragma unroll
  for (int t = 0; t < 12; ++t) {
    v[t] = __expf(v[t] - m);   // exp(-inf - m) = 0 handles diag
    s += v[t];
  }
#pragma unroll
  for (int o = 32; o; o >>= 1) s += __shfl_xor(s, o);
  __syncthreads();
  if (lane == 0) red[wave] = s;
  __syncthreads();
  s = red[0] + red[1] + red[2] + red[3];

  const float scale = ALPHA / s;
  __bf16* out = S + (size_t)i * G_DIM;
#pragma unroll
  for (int t = 0; t < 12; ++t) {
    int j = tid + t * 256;
    out[j] = (__bf16)(v[t] * scale);
  }
}

// ---------------- bf16 transpose ----------------
__global__ void transpose_k(const __bf16* __restrict__ in, __bf16* __restrict__ out) {
  __shared__ __bf16 t[32][33];
  const int bx = blockIdx.x * 32, by = blockIdx.y * 32;
  const int tx = threadIdx.x, ty = threadIdx.y;
#pragma unroll
  for (int k = 0; k < 32; k += 8)
    t[ty + k][tx] = in[(size_t)(by + ty + k) * G_DIM + bx + tx];
  __syncthreads();
#pragma unroll
  for (int k = 0; k < 32; k += 8)
    out[(size_t)(bx + ty + k) * G_DIM + by + tx] = t[tx][ty + k];
}

// ---------------- deinterleave channels into X [8192][G] bf16, row = rr*2 + c ------
// 384 threads/block, one block per rr; thread t handles g in [t*8, t*8+8)
__global__ __launch_bounds__(384) void deinterleave_k(const float* __restrict__ pg,
                                                      const float* __restrict__ gg,
                                                      __bf16* __restrict__ X) {
  const int rr = blockIdx.x;  // 0..4095
  const float* src = (rr < P_DIM) ? (pg + (size_t)rr * G_DIM * 2)
                                  : (gg + (size_t)(rr - P_DIM) * G_DIM * 2);
  const int t = threadIdx.x;
  const float4* s4 = (const float4*)(src + (size_t)t * 16);
  float4 a = s4[0], b = s4[1], c = s4[2], d = s4[3];
  bf16x8 v0, v1;
  v0[0] = (__bf16)a.x; v1[0] = (__bf16)a.y;
  v0[1] = (__bf16)a.z; v1[1] = (__bf16)a.w;
  v0[2] = (__bf16)b.x; v1[2] = (__bf16)b.y;
  v0[3] = (__bf16)b.z; v1[3] = (__bf16)b.w;
  v0[4] = (__bf16)c.x; v1[4] = (__bf16)c.y;
  v0[5] = (__bf16)c.z; v1[5] = (__bf16)c.w;
  v0[6] = (__bf16)d.x; v1[6] = (__bf16)d.y;
  v0[7] = (__bf16)d.z; v1[7] = (__bf16)d.w;
  *(bf16x8*)(X + (size_t)(rr * 2) * G_DIM + t * 8)     = v0;
  *(bf16x8*)(X + (size_t)(rr * 2 + 1) * G_DIM + t * 8) = v1;
}

// ---------------- staged global->LDS copy, pre-swizzled source (rule #21) ----------
// LDS tile: [128 rows][64 k] bf16 = 16 KiB, linear dest; read applies slot ^= (row&7)
__device__ __forceinline__ void stage128x64(const __bf16* __restrict__ src, size_t row0,
                                            int K, int k0, char* lds, int wave, int lane) {
#pragma unroll
  for (int q = 0; q < 4; ++q) {
    int seg = wave * 4 + q;
    int Lb = seg << 10;            // wave-uniform LDS byte base
    int L = Lb + lane * 16;        // this lane's dest byte
    int r = L >> 7;                // tile row
    int slot = ((L >> 4) & 7) ^ (r & 7);   // inverse swizzle on SOURCE
    const __bf16* g = src + (row0 + (size_t)r) * (size_t)K + (size_t)(k0 + slot * 8);
    __builtin_amdgcn_global_load_lds((const __attribute__((address_space(1))) void*)g,
                                     (__attribute__((address_space(3))) void*)(lds + Lb),
                                     16, 0, 0);
  }
}

// ---------------- NT GEMM: C[i,j] = sum_k A[i,k]*B[j,k] ----------------
// MODE 1: C bf16 = 0.9*(acc + e0[i,j])                  (W = 0.9*(S^2 + S))
// MODE 2: d_out f32 paired = acc + 0.9*orig f32         (propagate, X row = rr*2+c)
template <int MODE>
__global__ __launch_bounds__(256) void gemm_nt(const __bf16* __restrict__ A,
                                               const __bf16* __restrict__ B,
                                               void* __restrict__ C,
                                               const __bf16* __restrict__ e0,
                                               const float* __restrict__ pgin,
                                               const float* __restrict__ ggin,
                                               int M, int N, int K) {
  __shared__ int4 smem[2048];  // 32 KiB
  char* As = (char*)smem;
  char* Bs = (char*)smem + 16384;

  const int tid = threadIdx.x;
  const int wave = tid >> 6, lane = tid & 63;
  const int wm = wave >> 1, wn = wave & 1;   // 2x2 waves, each 64x64
  const int lr = lane & 15, g4 = lane >> 4;

  const size_t arow0 = (size_t)blockIdx.y * 128;
  const size_t brow0 = (size_t)blockIdx.x * 128;

  f32x4 acc[4][4] = {};

  const int nkt = K / 64;
  for (int kt = 0; kt < nkt; ++kt) {
    const int k0 = kt * 64;
    stage128x64(A, arow0, K, k0, As, wave, lane);
    stage128x64(B, brow0, K, k0, Bs, wave, lane);
    __syncthreads();

#pragma unroll
    for (int ks = 0; ks < 2; ++ks) {
      const int sA = (((ks * 4 + g4) ^ (lr & 7)) * 16);
      bf16x8 av[4], bv[4];
#pragma unroll
      for (int mf = 0; mf < 4; ++mf)
        av[mf] = *(const bf16x8*)(As + (wm * 64 + mf * 16 + lr) * 128 + sA);
#pragma unroll
      for (int nf = 0; nf < 4; ++nf)
        bv[nf] = *(const bf16x8*)(Bs + (wn * 64 + nf * 16 + lr) * 128 + sA);
#pragma unroll
      for (int mf = 0; mf < 4; ++mf)
#pragma unroll
        for (int nf = 0; nf < 4; ++nf)
          acc[mf][nf] = __builtin_amdgcn_mfma_f32_16x16x32_bf16(av[mf], bv[nf],
                                                                acc[mf][nf], 0, 0, 0);
    }
    __syncthreads();
  }

  // epilogue — C/D layout: col = lane&15, row = (lane>>4)*4 + reg  [measured m89/m91]
  const int r0 = (int)arow0 + wm * 64;
  const int c0 = (int)brow0 + wn * 64;
#pragma unroll
  for (int mf = 0; mf < 4; ++mf) {
#pragma unroll
    for (int nf = 0; nf < 4; ++nf) {
      const int col = c0 + nf * 16 + lr;
      if constexpr (MODE == 1) {
#pragma unroll
        for (int jj = 0; jj < 4; ++jj) {
          const int row = r0 + mf * 16 + g4 * 4 + jj;
          float w = 0.9f * (acc[mf][nf][jj] + (float)e0[(size_t)row * N + col]);
          ((__bf16*)C)[(size_t)row * N + col] = (__bf16)w;
        }
      } else {
        // rows come in (even,odd) pairs = (c=0, c=1) of original row rr
#pragma unroll
        for (int jp = 0; jp < 2; ++jp) {
          const int row = r0 + mf * 16 + g4 * 4 + jp * 2;  // even
          const int rr = row >> 1;
          const size_t base = (size_t)rr * G_DIM * 2 + (size_t)col * 2;
          const float* src = (rr < P_DIM) ? (pgin + base)
                                          : (ggin + base - (size_t)P_DIM * G_DIM * 2);
          float2 sv = *(const float2*)src;
          float2 ov;
          ov.x = acc[mf][nf][jp * 2]     + 0.9f * sv.x;
          ov.y = acc[mf][nf][jp * 2 + 1] + 0.9f * sv.y;
          *(float2*)((float*)C + base) = ov;
        }
      }
    }
  }
}

// ---------------- launch ----------------
extern "C" void kernel_launch(void* const* d_in, const int* in_sizes, int n_in,
                              void* d_out, int out_size, void* d_ws, size_t ws_size,
                              hipStream_t stream) {
  const float* pg = (const float*)d_in[0];  // [P,G,2] f32
  const float* gg = (const float*)d_in[1];  // [G,G,2] f32
  float* out = (float*)d_out;

  char* ws = (char*)d_ws;
  __bf16* S  = (__bf16*)(ws + S_OFF);
  __bf16* St = (__bf16*)(ws + ST_OFF);
  __bf16* W  = (__bf16*)(ws + W_OFF);
  __bf16* X  = (__bf16*)(ws + X_OFF);    // overlays S/St (dead by then)

  // 1. S = alpha * softmax(gg[:,:,1], -inf diag)      [G,G] bf16
  row_softmax_k<<<G_DIM, 256, 0, stream>>>(gg, S);
  // 2. St = S^T
  transpose_k<<<dim3(96, 96), dim3(32, 8), 0, stream>>>(S, St);
  // 3. W = 0.9*(S*S + S)   (NT: A=S, B=St; epilogue adds S, scales)
  gemm_nt<1><<<dim3(24, 24), 256, 0, stream>>>(S, St, W, S,
                                               nullptr, nullptr, G_DIM, G_DIM, G_DIM);
  // 4. X[rr*2+c][g] = bf16(src[rr][g][c])
  deinterleave_k<<<4096, 384, 0, stream>>>(pg, gg, X);
  // 5. out = X * W^T + 0.9 * X_f32, paired channels into d_out
  gemm_nt<2><<<dim3(24, 64), 256, 0, stream>>>(X, W, out, nullptr,
                                               pg, gg, 8192, G_DIM, G_DIM);
  (void)in_sizes; (void)n_in; (void)out_size; (void)ws_size;
}

// Round 3
// 289.516 us; speedup vs baseline: 1.6428x; 1.2334x over previous
//
#include <hip/hip_runtime.h>

// ---------------- problem constants ----------------
#define G_DIM 3072
#define P_DIM 1024
#define ALPHA 0.1f

typedef __attribute__((ext_vector_type(8))) __bf16 bf16x8;
typedef __attribute__((ext_vector_type(4))) float  f32x4;

// workspace layout (bytes), peak 69.2 MB
#define GG2      ((size_t)G_DIM * G_DIM * 2)          // bf16 G×G = 18,874,368 B
#define S_OFF    ((size_t)0)
#define ST_OFF   (GG2)
#define X_OFF    ((size_t)0)
#define XBYTES   ((size_t)8192 * G_DIM * 2)           // 50,331,648 B
#define W_OFF    (XBYTES)

// ---------------- softmax: S = alpha * softmax(scores, -inf diag) ----------------
__global__ __launch_bounds__(256) void row_softmax_k(const float* __restrict__ gg,
                                                     __bf16* __restrict__ S) {
  const int i = blockIdx.x;
  const float* row = gg + (size_t)i * G_DIM * 2;  // [G][2], channel 1
  const int tid = threadIdx.x;
  const int lane = tid & 63, wave = tid >> 6;

  float v[12];
  float m = -INFINITY;
#pragma unroll
  for (int t = 0; t < 12; ++t) {
    int j = tid + t * 256;
    float x = row[2 * j + 1];
    if (j == i) x = -INFINITY;
    v[t] = x;
    m = fmaxf(m, x);
  }
#pragma unroll
  for (int o = 32; o; o >>= 1) m = fmaxf(m, __shfl_xor(m, o));
  __shared__ float red[4];
  if (lane == 0) red[wave] = m;
  __syncthreads();
  m = fmaxf(fmaxf(red[0], red[1]), fmaxf(red[2], red[3]));

  float s = 0.f;
#pragma unroll
  for (int t = 0; t < 12; ++t) {
    v[t] = __expf(v[t] - m);
    s += v[t];
  }
#pragma unroll
  for (int o = 32; o; o >>= 1) s += __shfl_xor(s, o);
  __syncthreads();
  if (lane == 0) red[wave] = s;
  __syncthreads();
  s = red[0] + red[1] + red[2] + red[3];

  const float scale = ALPHA / s;
  __bf16* out = S + (size_t)i * G_DIM;
#pragma unroll
  for (int t = 0; t < 12; ++t) {
    int j = tid + t * 256;
    out[j] = (__bf16)(v[t] * scale);
  }
}

// ---------------- bf16 transpose ----------------
__global__ void transpose_k(const __bf16* __restrict__ in, __bf16* __restrict__ out) {
  __shared__ __bf16 t[32][33];
  const int bx = blockIdx.x * 32, by = blockIdx.y * 32;
  const int tx = threadIdx.x, ty = threadIdx.y;
#pragma unroll
  for (int k = 0; k < 32; k += 8)
    t[ty + k][tx] = in[(size_t)(by + ty + k) * G_DIM + bx + tx];
  __syncthreads();
#pragma unroll
  for (int k = 0; k < 32; k += 8)
    out[(size_t)(bx + ty + k) * G_DIM + by + tx] = t[tx][ty + k];
}

// ---------------- deinterleave channels into X [8192][G] bf16, row = rr*2 + c ------
__global__ __launch_bounds__(384) void deinterleave_k(const float* __restrict__ pg,
                                                      const float* __restrict__ gg,
                                                      __bf16* __restrict__ X) {
  const int rr = blockIdx.x;  // 0..4095
  const float* src = (rr < P_DIM) ? (pg + (size_t)rr * G_DIM * 2)
                                  : (gg + (size_t)(rr - P_DIM) * G_DIM * 2);
  const int t = threadIdx.x;
  const float4* s4 = (const float4*)(src + (size_t)t * 16);
  float4 a = s4[0], b = s4[1], c = s4[2], d = s4[3];
  bf16x8 v0, v1;
  v0[0] = (__bf16)a.x; v1[0] = (__bf16)a.y;
  v0[1] = (__bf16)a.z; v1[1] = (__bf16)a.w;
  v0[2] = (__bf16)b.x; v1[2] = (__bf16)b.y;
  v0[3] = (__bf16)b.z; v1[3] = (__bf16)b.w;
  v0[4] = (__bf16)c.x; v1[4] = (__bf16)c.y;
  v0[5] = (__bf16)c.z; v1[5] = (__bf16)c.w;
  v0[6] = (__bf16)d.x; v1[6] = (__bf16)d.y;
  v0[7] = (__bf16)d.z; v1[7] = (__bf16)d.w;
  *(bf16x8*)(X + (size_t)(rr * 2) * G_DIM + t * 8)     = v0;
  *(bf16x8*)(X + (size_t)(rr * 2 + 1) * G_DIM + t * 8) = v1;
}

// ------- staged global->LDS, pre-swizzled source (rule #21), 512 threads -------
// rows of 64 k-elems (128 B), linear LDS dest; read applies slot ^= (row&7)
template <int NISS>
__device__ __forceinline__ void stage_tile(const __bf16* __restrict__ src, size_t row0,
                                           int K, int k0, char* lds, int wave, int lane) {
#pragma unroll
  for (int q = 0; q < NISS; ++q) {
    int Lb = (wave * NISS + q) << 10;       // wave-uniform LDS byte base (1 KiB chunk)
    int L  = Lb + lane * 16;                // this lane's dest byte
    int r  = L >> 7;                        // tile row
    int slot = ((L >> 4) & 7) ^ (r & 7);    // inverse swizzle on SOURCE
    const __bf16* g = src + (row0 + (size_t)r) * (size_t)K + (size_t)(k0 + slot * 8);
    __builtin_amdgcn_global_load_lds((const __attribute__((address_space(1))) void*)g,
                                     (__attribute__((address_space(3))) void*)(lds + Lb),
                                     16, 0, 0);
  }
}

// ---------------- deep-pipelined NT GEMM: C[i,j] = sum_k A[i,k]*B[j,k] ----------------
// Tile 256x192, BK=64, 8 waves (2Mx4N), wave tile 128x48, depth-2 K pipeline,
// counted vmcnt(7) at tile top (T3+T4), setprio around MFMA clusters (T5).
// MODE 1: C bf16 = 0.9*(acc + e0[i,j])          (W = 0.9*(S^2 + S))
// MODE 2: d_out f32 paired = acc + 0.9*orig f32 (propagate, X row = rr*2+c)
template <int MODE>
__global__ __launch_bounds__(512, 2) void gemm8p(const __bf16* __restrict__ A,
                                                 const __bf16* __restrict__ B,
                                                 void* __restrict__ C,
                                                 const __bf16* __restrict__ e0,
                                                 const float* __restrict__ pgin,
                                                 const float* __restrict__ ggin,
                                                 int M, int N, int K) {
  // LDS: buf b at b*57344: A tile [256][64] (32 KiB) then B tile [192][64] (24 KiB)
  __shared__ char lds[114688];

  const int tid = threadIdx.x;
  const int wave = tid >> 6, lane = tid & 63;
  const int wm = wave >> 2, wn = wave & 3;   // 2M x 4N
  const int lr = lane & 15, g4 = lane >> 4;

  const size_t arow0 = (size_t)blockIdx.y * 256;
  const size_t brow0 = (size_t)blockIdx.x * 192;

  f32x4 acc[8][3] = {};
  const int NT = K / 64;

  // prologue: stage tiles 0 and 1
  stage_tile<4>(A, arow0, K, 0,  lds,         wave, lane);
  stage_tile<3>(B, brow0, K, 0,  lds + 32768, wave, lane);
  stage_tile<4>(A, arow0, K, 64, lds + 57344, wave, lane);
  stage_tile<3>(B, brow0, K, 64, lds + 57344 + 32768, wave, lane);

  for (int t = 0; t < NT; ++t) {
    char* As = lds + (t & 1) * 57344;
    char* Bs = As + 32768;

    // wait for THIS tile's 7 loads (tile t+1's 7 stay in flight) — never drain mid-loop
    if (t < NT - 1) asm volatile("s_waitcnt vmcnt(7)" ::: "memory");
    else            asm volatile("s_waitcnt vmcnt(0)" ::: "memory");
    __builtin_amdgcn_s_barrier();
    asm volatile("" ::: "memory");

    bf16x8 av[4][2], bv[3][2];
    // ---- phase 0: A rows [wm*128, +64), all B ----
#pragma unroll
    for (int mf = 0; mf < 4; ++mf)
#pragma unroll
      for (int ks = 0; ks < 2; ++ks)
        av[mf][ks] = *(const bf16x8*)(As + (wm * 128 + mf * 16 + lr) * 128 +
                                      (((ks * 4 + g4) ^ (lr & 7)) * 16));
#pragma unroll
    for (int nf = 0; nf < 3; ++nf)
#pragma unroll
      for (int ks = 0; ks < 2; ++ks)
        bv[nf][ks] = *(const bf16x8*)(Bs + (wn * 48 + nf * 16 + lr) * 128 +
                                      (((ks * 4 + g4) ^ (lr & 7)) * 16));
    __builtin_amdgcn_s_setprio(1);
#pragma unroll
    for (int mf = 0; mf < 4; ++mf)
#pragma unroll
      for (int nf = 0; nf < 3; ++nf)
#pragma unroll
        for (int ks = 0; ks < 2; ++ks)
          acc[mf][nf] = __builtin_amdgcn_mfma_f32_16x16x32_bf16(av[mf][ks], bv[nf][ks],
                                                                acc[mf][nf], 0, 0, 0);
    __builtin_amdgcn_s_setprio(0);

    // ---- phase 1: A rows [wm*128+64, +64), reuse bv ----
#pragma unroll
    for (int mf = 0; mf < 4; ++mf)
#pragma unroll
      for (int ks = 0; ks < 2; ++ks)
        av[mf][ks] = *(const bf16x8*)(As + (wm * 128 + 64 + mf * 16 + lr) * 128 +
                                      (((ks * 4 + g4) ^ (lr & 7)) * 16));
    __builtin_amdgcn_s_setprio(1);
#pragma unroll
    for (int mf = 0; mf < 4; ++mf)
#pragma unroll
      for (int nf = 0; nf < 3; ++nf)
#pragma unroll
        for (int ks = 0; ks < 2; ++ks)
          acc[4 + mf][nf] = __builtin_amdgcn_mfma_f32_16x16x32_bf16(av[mf][ks], bv[nf][ks],
                                                                    acc[4 + mf][nf], 0, 0, 0);
    __builtin_amdgcn_s_setprio(0);

    // all waves done reading buf[t&1] -> safe to overwrite with tile t+2
    __builtin_amdgcn_s_barrier();
    asm volatile("" ::: "memory");
    if (t + 2 < NT) {
      stage_tile<4>(A, arow0, K, (t + 2) * 64, As, wave, lane);
      stage_tile<3>(B, brow0, K, (t + 2) * 64, Bs, wave, lane);
    }
  }

  // epilogue — C/D layout: col = lane&15, row = (lane>>4)*4 + reg  [measured m89/m91]
  const int r0 = (int)arow0 + wm * 128;
  const int c0 = (int)brow0 + wn * 48;
#pragma unroll
  for (int mf = 0; mf < 8; ++mf) {
#pragma unroll
    for (int nf = 0; nf < 3; ++nf) {
      const int col = c0 + nf * 16 + lr;
      if constexpr (MODE == 1) {
#pragma unroll
        for (int jj = 0; jj < 4; ++jj) {
          const int row = r0 + mf * 16 + g4 * 4 + jj;
          float w = 0.9f * (acc[mf][nf][jj] + (float)e0[(size_t)row * N + col]);
          ((__bf16*)C)[(size_t)row * N + col] = (__bf16)w;
        }
      } else {
        // rows come in (even,odd) pairs = (c=0, c=1) of original row rr
#pragma unroll
        for (int jp = 0; jp < 2; ++jp) {
          const int row = r0 + mf * 16 + g4 * 4 + jp * 2;  // even
          const int rr = row >> 1;
          const size_t base = (size_t)rr * G_DIM * 2 + (size_t)col * 2;
          const float* src = (rr < P_DIM) ? (pgin + base)
                                          : (ggin + base - (size_t)P_DIM * G_DIM * 2);
          float2 sv = *(const float2*)src;
          float2 ov;
          ov.x = acc[mf][nf][jp * 2]     + 0.9f * sv.x;
          ov.y = acc[mf][nf][jp * 2 + 1] + 0.9f * sv.y;
          *(float2*)((float*)C + base) = ov;
        }
      }
    }
  }
}

// ---------------- launch ----------------
extern "C" void kernel_launch(void* const* d_in, const int* in_sizes, int n_in,
                              void* d_out, int out_size, void* d_ws, size_t ws_size,
                              hipStream_t stream) {
  const float* pg = (const float*)d_in[0];  // [P,G,2] f32
  const float* gg = (const float*)d_in[1];  // [G,G,2] f32
  float* out = (float*)d_out;

  char* ws = (char*)d_ws;
  __bf16* S  = (__bf16*)(ws + S_OFF);
  __bf16* St = (__bf16*)(ws + ST_OFF);
  __bf16* W  = (__bf16*)(ws + W_OFF);
  __bf16* X  = (__bf16*)(ws + X_OFF);    // overlays S/St (dead by then)

  // 1. S = alpha * softmax(gg[:,:,1], -inf diag)      [G,G] bf16
  row_softmax_k<<<G_DIM, 256, 0, stream>>>(gg, S);
  // 2. St = S^T
  transpose_k<<<dim3(96, 96), dim3(32, 8), 0, stream>>>(S, St);
  // 3. W = 0.9*(S*S + S)   (NT: A=S, B=St; epilogue adds S, scales)
  gemm8p<1><<<dim3(16, 12), 512, 0, stream>>>(S, St, W, S,
                                              nullptr, nullptr, G_DIM, G_DIM, G_DIM);
  // 4. X[rr*2+c][g] = bf16(src[rr][g][c])
  deinterleave_k<<<4096, 384, 0, stream>>>(pg, gg, X);
  // 5. out = X * W^T + 0.9 * X_f32, paired channels into d_out
  gemm8p<2><<<dim3(16, 32), 512, 0, stream>>>(X, W, out, nullptr,
                                              pg, gg, 8192, G_DIM, G_DIM);
  (void)in_sizes; (void)n_in; (void)out_size; (void)ws_size;
}